// Round 1
// baseline (210.712 us; speedup 1.0000x reference)
//
#include <hip/hip_runtime.h>
#include <stdint.h>

typedef __attribute__((ext_vector_type(4)))  int   intx4;
typedef __attribute__((ext_vector_type(8)))  int   intx8;
typedef __attribute__((ext_vector_type(16))) float floatx16;

#define GLL16(gp, lp)                                                               \
    __builtin_amdgcn_global_load_lds((const __attribute__((address_space(1))) unsigned int*)(gp), \
                                     (__attribute__((address_space(3))) unsigned int*)(lp), 16, 0, 0)
#define GLL4(gp, lp)                                                                \
    __builtin_amdgcn_global_load_lds((const __attribute__((address_space(1))) unsigned int*)(gp), \
                                     (__attribute__((address_space(3))) unsigned int*)(lp), 4, 0, 0)

// ---------------------------------------------------------------------------
// RTE onto the e2m1 grid {0,.5,1,1.5,2,3,4,6} -> code 0..7 (ties-to-even,
// matches ref searchsorted+tie-fix). Sign -> bit 3. (unchanged, proven)
// ---------------------------------------------------------------------------
__device__ __forceinline__ uint32_t enc1(float xv, float inv) {
    float a = fminf(fabsf(xv) * inv, 6.0f);
    int e;
    if (a < 2.0f)      e = (int)rintf(a + a);          // 0,.5,1,1.5,2 -> 0..4
    else if (a < 4.0f) e = (int)rintf(a) + 2;          // 2,3,4        -> 4..6
    else               e = (int)rintf(a * 0.5f) + 4;   // 4,6          -> 6,7
    return (uint32_t)e | ((__float_as_uint(xv) >> 28) & 8u);
}

// ---------------------------------------------------------------------------
// Kernel 1: quantize x. One lane = one float4 (4 elements); 8 lanes = one MX
// block of 32. Block max via 3x shfl_xor within the 8-lane group. Every
// global access (float4 load, uint16 nibble store, scale byte store) is
// lane-consecutive -> fully coalesced. Scales go to NATURAL layout
// xs[m*kbpr + kb] (= xs[block]) — no transpose scatter.
// ---------------------------------------------------------------------------
__global__ __launch_bounds__(256) void quant_x_kernel(const float* __restrict__ x,
                                                      uint32_t* __restrict__ xq,
                                                      uint8_t* __restrict__ xs) {
    const int gl = blockIdx.x * 256 + threadIdx.x;          // lane over M*K/4
    const float4 v = ((const float4*)x)[gl];
    float m = fmaxf(fmaxf(fabsf(v.x), fabsf(v.y)), fmaxf(fabsf(v.z), fabsf(v.w)));
    m = fmaxf(m, __shfl_xor(m, 1));
    m = fmaxf(m, __shfl_xor(m, 2));
    m = fmaxf(m, __shfl_xor(m, 4));                         // 8-lane group = 1 MX block
    // FLOOR scale: e8m0 code = exp_field(max) - 2, clamped so scale >= 2^-126
    const unsigned ef = __float_as_uint(m) >> 23;
    const unsigned code = (ef < 3u) ? 1u : (ef - 2u);
    const float inv = __uint_as_float((254u - code) << 23); // exact 2^(127-code)
    const uint32_t p = enc1(v.x, inv)        | (enc1(v.y, inv) << 4)
                     | (enc1(v.z, inv) << 8) | (enc1(v.w, inv) << 12);
    ((uint16_t*)xq)[gl] = (uint16_t)p;                      // coalesced 2 B/lane
    if ((gl & 7) == 0) xs[gl >> 3] = (uint8_t)code;         // coalesced byte/8 lanes
}

// ---------------------------------------------------------------------------
// Kernel 2: merged repack. Part A: densify weight nibbles (one packed byte
// per int32 -> uint8 array). Part B: weight scales int32 -> uint8, NATURAL
// layout ws[n*kbpr + kb] (no transpose). Both fully coalesced.
// ---------------------------------------------------------------------------
__global__ __launch_bounds__(256) void repack_kernel(const int* __restrict__ wp,
                                                     uint32_t* __restrict__ wrep,
                                                     int n4w,
                                                     const int* __restrict__ wsc,
                                                     uint32_t* __restrict__ ws,
                                                     int n4s) {
    const int t = blockIdx.x * 256 + threadIdx.x;
    if (t < n4w) {
        const int4 p = ((const int4*)wp)[t];
        wrep[t] = (uint32_t)(p.x & 0xFF) | ((uint32_t)(p.y & 0xFF) << 8)
                | ((uint32_t)(p.z & 0xFF) << 16) | ((uint32_t)(p.w & 0xFF) << 24);
    } else if (t - n4w < n4s) {
        const int i = t - n4w;
        const int4 p = ((const int4*)wsc)[i];
        ws[i] = (uint32_t)(p.x & 0xFF) | ((uint32_t)(p.y & 0xFF) << 8)
              | ((uint32_t)(p.z & 0xFF) << 16) | ((uint32_t)(p.w & 0xFF) << 24);
    }
}

// ---------------------------------------------------------------------------
// Kernel 3: MXFP4 GEMM, 128x128 tile, BK=128, 4 waves x (2x2)
// v_mfma_scale_f32_32x32x64_f8f6f4 (fmt 4 = fp4 e2m1).
//
// This round: double-buffered LDS + prefetch-1 with COUNTED vmcnt(5)
// (5 VMEM/wave/chunk: 4x GLL16 data + 1x GLL4 scales) and raw s_barrier —
// chunk c+1's loads stay in flight while chunk c computes (T3/T4-lite).
// Scales live in LDS as [row][kb0..3] (natural layout): one ds_read_b32 per
// row, lanes 0-31 hit 32 consecutive dwords (conflict-free), lanes 32-63
// broadcast — replaces the banks-0..7 byte reads that caused 12.6M conflict
// cycles. setprio(1) wraps the MFMA cluster (T5).
// ---------------------------------------------------------------------------
__global__ __launch_bounds__(256) void gemm_mx_kernel(const uint8_t* __restrict__ Apk,
                                                      const uint8_t* __restrict__ Bpk,
                                                      const uint8_t* __restrict__ As,
                                                      const uint8_t* __restrict__ Bs,
                                                      float* __restrict__ C,
                                                      int M, int N, int K) {
    __shared__ __align__(16) uint8_t sA[2][8192];   // 128 rows x 64 B, dbuf
    __shared__ __align__(16) uint8_t sB[2][8192];
    __shared__ __align__(16) uint8_t sS[2][1024];   // [buf][A rows 0..127 | B rows 0..127] x 4 B

    const int tid = threadIdx.x;
    const int bm0 = blockIdx.y << 7;
    const int bn0 = blockIdx.x << 7;
    const int wave = tid >> 6;
    const int lane = tid & 63;
    const int wm = (wave >> 1) << 6;
    const int wn = (wave & 1) << 6;
    const int row = lane & 31;
    const int h = lane >> 5;
    const int Kb = K >> 1;                          // packed bytes per row
    const int kbpr = K >> 5;                        // scale bytes per row

    // data staging: slot s covers LDS [16s,16s+16); content = row s>>2,
    // piece p = (s&3) ^ (row&3)  (XOR swizzle, involution)
    const int s0 = tid, s1 = tid + 256;
    const int r0 = s0 >> 2, p0 = (s0 & 3) ^ (r0 & 3);
    const int r1 = s1 >> 2, p1 = (s1 & 3) ^ (r1 & 3);
    const uint8_t* Ag0 = Apk + (size_t)(bm0 + r0) * Kb + p0 * 16;
    const uint8_t* Ag1 = Apk + (size_t)(bm0 + r1) * Kb + p1 * 16;
    const uint8_t* Bg0 = Bpk + (size_t)(bn0 + r0) * Kb + p0 * 16;
    const uint8_t* Bg1 = Bpk + (size_t)(bn0 + r1) * Kb + p1 * 16;

    // scale staging: waves 0-1 -> A rows 0..127, waves 2-3 -> B rows 0..127.
    // Global src per-lane (row-major gather); LDS dest = wave base + lane*4.
    const int srow = tid & 127;
    const uint8_t* Sg = (tid < 128) ? (As + (size_t)(bm0 + srow) * kbpr)
                                    : (Bs + (size_t)(bn0 + srow) * kbpr);
    const int sldoff = ((tid < 128) ? 0 : 512) + srow * 4;

    floatx16 acc[2][2];
#pragma unroll
    for (int a = 0; a < 2; ++a)
#pragma unroll
        for (int b = 0; b < 2; ++b)
#pragma unroll
            for (int r = 0; r < 16; ++r) acc[a][b][r] = 0.f;

    const int nchunk = K >> 7;                      // 32

    auto STAGE = [&](int bf, int c) {
        const size_t koff = (size_t)c << 6;         // 64 B per chunk
        GLL16(Ag0 + koff, &sA[bf][s0 * 16]);
        GLL16(Ag1 + koff, &sA[bf][s1 * 16]);
        GLL16(Bg0 + koff, &sB[bf][s0 * 16]);
        GLL16(Bg1 + koff, &sB[bf][s1 * 16]);
        GLL4(Sg + (size_t)c * 4, &sS[bf][sldoff]);
    };

    const int ar0 = wm + row, ar1 = wm + 32 + row;
    const int br0 = wn + row, br1 = wn + 32 + row;

    auto COMPUTE = [&](int bf) {
        // all 4 scale codes (kb 4c..4c+3) per row in one conflict-free b32
        const uint32_t saw0 = *(const uint32_t*)&sS[bf][ar0 * 4];
        const uint32_t saw1 = *(const uint32_t*)&sS[bf][ar1 * 4];
        const uint32_t sbw0 = *(const uint32_t*)&sS[bf][512 + br0 * 4];
        const uint32_t sbw1 = *(const uint32_t*)&sS[bf][512 + br1 * 4];
#pragma unroll
        for (int s = 0; s < 2; ++s) {
            const int kp = 2 * s + h;               // 16B piece index 0..3
            const int sh = kp * 8;
            intx4 a4[2], b4[2];
            a4[0] = *(const intx4*)&sA[bf][ar0 * 64 + ((kp ^ (ar0 & 3)) << 4)];
            a4[1] = *(const intx4*)&sA[bf][ar1 * 64 + ((kp ^ (ar1 & 3)) << 4)];
            b4[0] = *(const intx4*)&sB[bf][br0 * 64 + ((kp ^ (br0 & 3)) << 4)];
            b4[1] = *(const intx4*)&sB[bf][br1 * 64 + ((kp ^ (br1 & 3)) << 4)];
            const int sa[2] = { (int)((saw0 >> sh) & 0xFF), (int)((saw1 >> sh) & 0xFF) };
            const int sb[2] = { (int)((sbw0 >> sh) & 0xFF), (int)((sbw1 >> sh) & 0xFF) };
            __builtin_amdgcn_s_setprio(1);
#pragma unroll
            for (int mt = 0; mt < 2; ++mt)
#pragma unroll
                for (int nt = 0; nt < 2; ++nt) {
                    intx8 a8 = {a4[mt][0], a4[mt][1], a4[mt][2], a4[mt][3], 0, 0, 0, 0};
                    intx8 b8 = {b4[nt][0], b4[nt][1], b4[nt][2], b4[nt][3], 0, 0, 0, 0};
                    acc[mt][nt] = __builtin_amdgcn_mfma_scale_f32_32x32x64_f8f6f4(
                        a8, b8, acc[mt][nt], 4, 4, 0, sa[mt], 0, sb[nt]);
                }
            __builtin_amdgcn_s_setprio(0);
        }
    };

    // prologue: stage chunk 0 into buf 0
    STAGE(0, 0);
    // main loop: stage c+1 into the other buffer, wait only for chunk c's 5
    // loads (vmcnt(5) leaves the 5 just-issued in flight), compute chunk c.
    // Second barrier protects buf reuse: iter c+1's STAGE overwrites the
    // buffer iter c just read.
    for (int c = 0; c < nchunk - 1; ++c) {
        const int bf = c & 1;
        STAGE(bf ^ 1, c + 1);
        asm volatile("s_waitcnt vmcnt(5)" ::: "memory");
        __builtin_amdgcn_s_barrier();
        COMPUTE(bf);
        __builtin_amdgcn_s_barrier();
    }
    // epilogue: last chunk (no prefetch outstanding target -> drain)
    asm volatile("s_waitcnt vmcnt(0)" ::: "memory");
    __builtin_amdgcn_s_barrier();
    COMPUTE((nchunk - 1) & 1);

    // C/D layout (32x32): col = lane&31, row = (reg&3) + 8*(reg>>2) + 4*(lane>>5)
#pragma unroll
    for (int mt = 0; mt < 2; ++mt)
#pragma unroll
        for (int nt = 0; nt < 2; ++nt) {
            const int col = bn0 + wn + nt * 32 + row;
#pragma unroll
            for (int g = 0; g < 4; ++g) {
                const int rw = bm0 + wm + mt * 32 + 8 * g + 4 * h;
#pragma unroll
                for (int q = 0; q < 4; ++q)
                    C[(size_t)(rw + q) * N + col] = acc[mt][nt][4 * g + q];
            }
        }
}

// ---------------------------------------------------------------------------
extern "C" void kernel_launch(void* const* d_in, const int* in_sizes, int n_in,
                              void* d_out, int out_size, void* d_ws, size_t ws_size,
                              hipStream_t stream) {
    const float* x = (const float*)d_in[0];
    const int* wp = (const int*)d_in[1];
    const int* wsc = (const int*)d_in[2];
    float* out = (float*)d_out;

    const int K = 4096;
    const int M = in_sizes[0] / K;            // 4096
    const int N = (in_sizes[1] * 2) / K;      // 4096
    const int kbpr = K / 32;                  // 128
    const int npack = N * K / 2;              // weight packed bytes

    uint32_t* xq   = (uint32_t*)d_ws;                                  // 8 MiB
    uint8_t*  xs   = (uint8_t*)d_ws + (size_t)M * K / 2;               // 512 KiB (natural [m][kb])
    uint8_t*  ws   = xs + (size_t)M * kbpr;                            // 512 KiB (natural [n][kb])
    uint32_t* wrep = (uint32_t*)(ws + (size_t)N * kbpr);               // 8 MiB

    const int n4w = npack / 4;
    const int n4s = (N * kbpr) / 4;

    quant_x_kernel<<<(M * K / 4) / 256, 256, 0, stream>>>(x, xq, xs);
    repack_kernel<<<(n4w + n4s + 255) / 256, 256, 0, stream>>>(wp, wrep, n4w,
                                                               wsc, (uint32_t*)ws, n4s);

    dim3 grid(N / 128, M / 128);
    gemm_mx_kernel<<<grid, 256, 0, stream>>>((const uint8_t*)xq, (const uint8_t*)wrep,
                                             xs, ws, out, M, N, K);
}